// Round 8
// baseline (602.527 us; speedup 1.0000x reference)
//
#include <hip/hip_runtime.h>
#include <cstddef>
#include <cstdint>

#define USER_COUNT_C 100000
#define ITEM_COUNT_C 100000
#define DIM_C 64
#define B_C 1024
#define NPOS_C 10
#define NTOP_C 50
#define CLAMP_C 40.0f
#define EPS_C 1e-5f

#define NGROUPS 6250          // 100000/16 item groups (exact)
#define GX 48                 // item-range blocks
#define GY 16                 // user blocks (64 users each); 768 blocks = 3/CU

using bf16x8 = __attribute__((ext_vector_type(8))) short;
using f32x4  = __attribute__((ext_vector_type(4))) float;

__global__ void zero_ws_kernel(float* __restrict__ ws) {
    ws[threadIdx.x] = 0.0f;  // B_C threads
}

// RNE fp32 -> bf16 bits
__device__ inline short f2bf(float x) {
    uint32_t b = __float_as_uint(x);
    uint32_t r = (b + 0x7fffu + ((b >> 16) & 1u)) >> 16;
    return (short)r;
}

__device__ inline bf16x8 cvt8(const float* __restrict__ p) {
    float4 v0 = *(const float4*)p;
    float4 v1 = *(const float4*)(p + 4);
    bf16x8 r;
    r[0] = f2bf(v0.x); r[1] = f2bf(v0.y); r[2] = f2bf(v0.z); r[3] = f2bf(v0.w);
    r[4] = f2bf(v1.x); r[5] = f2bf(v1.y); r[6] = f2bf(v1.z); r[7] = f2bf(v1.w);
    return r;
}

// item_bf16 frag-ready layout: group g (16 items), half h (k 0/1), quad q,
// item idx16: 8 bf16 at (g*1024 + h*512 + q*128 + idx16*8). Wave frag = 1KB.
__global__ __launch_bounds__(256) void prep_items_kernel(
    const float* __restrict__ item_emb, short* __restrict__ item_bf16) {
    const int t = blockIdx.x * 256 + threadIdx.x;   // NGROUPS*128 total (exact)
    const int n16 = t & 15;
    const int q   = (t >> 4) & 3;
    const int h   = (t >> 6) & 1;
    const int g   = t >> 7;
    const int i   = g * 16 + n16;                   // always < ITEM_COUNT_C
    bf16x8 v = cvt8(item_emb + (size_t)i * DIM_C + h * 32 + q * 8);
    *(bf16x8*)(item_bf16 + (size_t)g * 1024 + h * 512 + q * 128 + n16 * 8) = v;
}

// exp_sum[b] = sum_i exp(clip(u_b . item_i, +-40)) * (1 - mask[b][i])
// ITEMS in A, USERS in B (C: row=item quad*4+r, col=user n16). Wave owns 64
// users (4 resident B-frag pairs). TRUE register double-buffer: batch t+1's
// 6 VMEM are issued before computing batch t, so the compiler's per-register
// waitcnt leaves them in flight across the compute phase (vmcnt(6), never 0).
__global__ __launch_bounds__(256, 3) void expsum_mfma7_kernel(
    const float* __restrict__ user_emb,
    const short* __restrict__ item_bf16,
    const int*   __restrict__ batch_user,
    const float* __restrict__ mask,
    float*       __restrict__ exp_sum)
{
    const int tid  = threadIdx.x;
    const int wave = tid >> 6;
    const int lane = tid & 63;
    const int n16  = lane & 15;   // user-in-group / item-in-group index
    const int quad = lane >> 4;   // k-group; C row-group (items)
    const int uBase = blockIdx.y * 64;

    // B fragments: 4 user groups (j*16+n16), resident all kernel
    bf16x8 b0[4], b1[4];
    #pragma unroll
    for (int j = 0; j < 4; ++j) {
        const int uidx = batch_user[uBase + j * 16 + n16];
        const float* us = user_emb + (size_t)uidx * DIM_C + quad * 8;
        b0[j] = cvt8(us);
        b1[j] = cvt8(us + 32);
    }

    // lane's mask base: row = user uBase + j*16 + n16, col = c*16 + quad*4
    const float* mbase = mask + (size_t)(uBase + n16) * ITEM_COUNT_C + quad * 4;
    const short* fbase = item_bf16 + quad * 128 + n16 * 8;

    const int c0   = (int)(((long)blockIdx.x * NGROUPS) / GX);
    const int cEnd = (int)(((long)(blockIdx.x + 1) * NGROUPS) / GX);

    float accE[4] = {0.f, 0.f, 0.f, 0.f};

    // double-buffer registers (disjoint A/B batches; no copies between them)
    bf16x8 fA0, fA1, fB0, fB1;
    float4 mA[4], mB[4];

    auto loadA = [&](int c) {
        const short* fp = fbase + (size_t)c * 1024;
        fA0 = *(const bf16x8*)fp;
        fA1 = *(const bf16x8*)(fp + 512);
        #pragma unroll
        for (int j = 0; j < 4; ++j)
            mA[j] = *(const float4*)(mbase + (size_t)j * 16 * ITEM_COUNT_C + (size_t)c * 16);
    };
    auto loadB = [&](int c) {
        const short* fp = fbase + (size_t)c * 1024;
        fB0 = *(const bf16x8*)fp;
        fB1 = *(const bf16x8*)(fp + 512);
        #pragma unroll
        for (int j = 0; j < 4; ++j)
            mB[j] = *(const float4*)(mbase + (size_t)j * 16 * ITEM_COUNT_C + (size_t)c * 16);
    };
    auto computeA = [&]() {
        f32x4 acc[4];
        #pragma unroll
        for (int j = 0; j < 4; ++j) {
            acc[j] = (f32x4){0.f, 0.f, 0.f, 0.f};
            acc[j] = __builtin_amdgcn_mfma_f32_16x16x32_bf16(fA0, b0[j], acc[j], 0, 0, 0);
            acc[j] = __builtin_amdgcn_mfma_f32_16x16x32_bf16(fA1, b1[j], acc[j], 0, 0, 0);
        }
        #pragma unroll
        for (int j = 0; j < 4; ++j) {
            const float* mp = (const float*)&mA[j];
            #pragma unroll
            for (int r = 0; r < 4; ++r) {
                const float sc = fminf(fmaxf(acc[j][r], -CLAMP_C), CLAMP_C);
                accE[j] += __expf(sc) * (1.0f - mp[r]);
            }
        }
    };
    auto computeB = [&]() {
        f32x4 acc[4];
        #pragma unroll
        for (int j = 0; j < 4; ++j) {
            acc[j] = (f32x4){0.f, 0.f, 0.f, 0.f};
            acc[j] = __builtin_amdgcn_mfma_f32_16x16x32_bf16(fB0, b0[j], acc[j], 0, 0, 0);
            acc[j] = __builtin_amdgcn_mfma_f32_16x16x32_bf16(fB1, b1[j], acc[j], 0, 0, 0);
        }
        #pragma unroll
        for (int j = 0; j < 4; ++j) {
            const float* mp = (const float*)&mB[j];
            #pragma unroll
            for (int r = 0; r < 4; ++r) {
                const float sc = fminf(fmaxf(acc[j][r], -CLAMP_C), CLAMP_C);
                accE[j] += __expf(sc) * (1.0f - mp[r]);
            }
        }
    };

    int c = c0 + wave;
    if (c < cEnd) {
        loadA(c);
        for (;;) {
            int cn = c + 4;
            bool more = cn < cEnd;
            loadB(more ? cn : c);      // dummy reload if last (discarded)
            computeA();
            if (!more) break;
            c = cn;
            cn = c + 4;
            more = cn < cEnd;
            loadA(more ? cn : c);
            computeB();
            if (!more) break;
            c = cn;
        }
    }

    // reduce over quads (lane bits 4,5): each user's partial lives in 4 lanes
    #pragma unroll
    for (int j = 0; j < 4; ++j) {
        accE[j] += __shfl_xor(accE[j], 16, 64);
        accE[j] += __shfl_xor(accE[j], 32, 64);
    }
    if (quad == 0) {
        #pragma unroll
        for (int j = 0; j < 4; ++j)
            atomicAdd(&exp_sum[uBase + j * 16 + n16], accE[j]);
    }
}

// Fallback (ws too small for bf16 item buffer): fp32 items from global
__global__ __launch_bounds__(256) void expsum_fallback_kernel(
    const float* __restrict__ user_emb,
    const float* __restrict__ item_emb,
    const int*   __restrict__ batch_user,
    const float* __restrict__ mask,
    float*       __restrict__ exp_sum)
{
    const int tid  = threadIdx.x;
    const int wave = tid >> 6;
    const int lane = tid & 63;
    const int n16  = lane & 15;
    const int quad = lane >> 4;
    const int rowBase = blockIdx.y * 64 + wave * 16;

    const int uidx = batch_user[rowBase + n16];
    const float* usrc = user_emb + (size_t)uidx * DIM_C + quad * 8;
    const bf16x8 a0 = cvt8(usrc);
    const bf16x8 a1 = cvt8(usrc + 32);

    float accExp[4] = {0.f, 0.f, 0.f, 0.f};

    for (int t = blockIdx.x; t < NGROUPS / 4; t += 64) {
        const int ibase = t * 64;
        bf16x8 b0[4], b1[4];
        #pragma unroll
        for (int s = 0; s < 4; ++s) {
            const int gi = ibase + s * 16 + n16;
            const float* isrc = item_emb + (size_t)gi * DIM_C + quad * 8;
            b0[s] = cvt8(isrc);
            b1[s] = cvt8(isrc + 32);
        }
        f32x4 acc[4];
        #pragma unroll
        for (int s = 0; s < 4; ++s) {
            acc[s] = (f32x4){0.f, 0.f, 0.f, 0.f};
            acc[s] = __builtin_amdgcn_mfma_f32_16x16x32_bf16(a0, b0[s], acc[s], 0, 0, 0);
            acc[s] = __builtin_amdgcn_mfma_f32_16x16x32_bf16(a1, b1[s], acc[s], 0, 0, 0);
        }
        #pragma unroll
        for (int s = 0; s < 4; ++s)
            #pragma unroll
            for (int reg = 0; reg < 4; ++reg) {
                const int row = rowBase + quad * 4 + reg;
                const float sc = fminf(fmaxf(acc[s][reg], -CLAMP_C), CLAMP_C);
                const float w = 1.0f - mask[(size_t)row * ITEM_COUNT_C + ibase + s * 16 + n16];
                accExp[reg] += __expf(sc) * w;
            }
    }
    #pragma unroll
    for (int off = 1; off < 16; off <<= 1)
        #pragma unroll
        for (int reg = 0; reg < 4; ++reg)
            accExp[reg] += __shfl_xor(accExp[reg], off, 64);
    if (n16 == 0)
        #pragma unroll
        for (int reg = 0; reg < 4; ++reg)
            atomicAdd(&exp_sum[rowBase + quad * 4 + reg], accExp[reg]);
}

// per-row: 60 sampled scores (exact fp32) + loss math -> row_loss[b]
__global__ void finalize_kernel(
    const float* __restrict__ user_emb,
    const float* __restrict__ item_emb,
    const int*   __restrict__ batch_user,
    const int*   __restrict__ pos_items,
    const int*   __restrict__ top_items,
    const float* __restrict__ exp_sum,
    const int*   __restrict__ is_final,
    float*       __restrict__ row_loss)
{
    __shared__ float ush[DIM_C];
    __shared__ float s_sh[NPOS_C + NTOP_C];
    const int b = blockIdx.x;
    const int tid = threadIdx.x;  // 64 threads
    const int uidx = batch_user[b];
    if (tid < 16)
        *(float4*)&ush[tid * 4] = *(const float4*)(user_emb + (size_t)uidx * DIM_C + tid * 4);
    __syncthreads();

    if (tid < NPOS_C + NTOP_C) {
        const int idx = (tid < NPOS_C) ? pos_items[b * NPOS_C + tid]
                                       : top_items[b * NTOP_C + (tid - NPOS_C)];
        const float* iv = item_emb + (size_t)idx * DIM_C;
        float s = 0.f;
        #pragma unroll
        for (int d4 = 0; d4 < 16; ++d4) {
            const float4 a = *(const float4*)(iv + d4 * 4);
            s += a.x * ush[d4 * 4 + 0] + a.y * ush[d4 * 4 + 1]
               + a.z * ush[d4 * 4 + 2] + a.w * ush[d4 * 4 + 3];
        }
        s_sh[tid] = fminf(fmaxf(s, -CLAMP_C), CLAMP_C);
    }
    __syncthreads();

    if (tid == 0) {
        const float E = exp_sum[b];
        float L;
        if (is_final[0] != 0) {
            float sumExpTop = 0.f, above_top = 0.f;
            for (int i = 0; i < NTOP_C / 2; ++i) {
                const float v = s_sh[NPOS_C + i];
                sumExpTop += __expf(v); above_top += v;
            }
            const float below2 = E - sumExpTop;
            float above_pos = 0.f;
            for (int i = 0; i < NPOS_C; ++i) above_pos += s_sh[i];
            float c = 0.f, below_pos = 0.f;
            for (int i = 0; i < NPOS_C; ++i) {
                c += __expf(s_sh[NPOS_C - 1 - i]);
                below_pos += __logf(fmaxf(c + below2, EPS_C));
            }
            float c2 = 0.f, below_top = 0.f;
            for (int i = 0; i < NTOP_C / 2; ++i) {
                c2 += __expf(s_sh[NPOS_C + NTOP_C / 2 - 1 - i]);
                below_top += __logf(fmaxf(c2 + below2, EPS_C));
            }
            const float pos_KD = below_pos - above_pos;
            float sumExpSub = 0.f, above_sub = 0.f;
            for (int i = 0; i < NTOP_C / 10; ++i) {
                const float v = s_sh[NPOS_C + i];
                sumExpSub += __expf(v); above_sub += v;
            }
            const float below2s = E - sumExpSub;
            float c3 = 0.f, below_sub = 0.f;
            for (int i = 0; i < NTOP_C / 10; ++i) {
                c3 += __expf(s_sh[NPOS_C + NTOP_C / 10 - 1 - i]);
                below_sub += __logf(fmaxf(c3 + below2s, EPS_C));
            }
            const float top_KD = (below_top - above_top) + (below_sub - above_sub);
            L = pos_KD + 0.5f * top_KD;
        } else {
            float sumExpTop = 0.f;
            for (int i = 0; i < NTOP_C; ++i) sumExpTop += __expf(s_sh[NPOS_C + i]);
            const float els = E - sumExpTop;
            L = 0.f;
            for (int j = 0; j < NPOS_C + NTOP_C; ++j) {
                const float a = s_sh[j];
                L += __logf(fmaxf(els + __expf(a), EPS_C)) - a;
            }
        }
        row_loss[b] = L;
    }
}

__global__ void reduce_kernel(const float* __restrict__ rl, float* __restrict__ out) {
    __shared__ float part[16];
    const int tid = threadIdx.x;  // 1024 threads = 16 waves
    float v = rl[tid];
    #pragma unroll
    for (int off = 32; off > 0; off >>= 1) v += __shfl_down(v, off, 64);
    if ((tid & 63) == 0) part[tid >> 6] = v;
    __syncthreads();
    if (tid == 0) {
        float s = 0.f;
        #pragma unroll
        for (int i = 0; i < 16; ++i) s += part[i];
        out[0] = s;
    }
}

extern "C" void kernel_launch(void* const* d_in, const int* in_sizes, int n_in,
                              void* d_out, int out_size, void* d_ws, size_t ws_size,
                              hipStream_t stream) {
    const float* user_emb   = (const float*)d_in[0];
    const float* item_emb   = (const float*)d_in[1];
    const int*   batch_user = (const int*)d_in[2];
    const int*   pos_items  = (const int*)d_in[3];
    const int*   top_items  = (const int*)d_in[4];
    const float* mask       = (const float*)d_in[5];
    const int*   is_final   = (const int*)d_in[6];
    float* out = (float*)d_out;

    float* exp_sum  = (float*)d_ws;       // [B_C]
    float* row_loss = exp_sum + B_C;      // [B_C]
    short* item_bf16 = (short*)(row_loss + B_C);
    const size_t need = 2 * B_C * sizeof(float)
                      + ((size_t)NGROUPS + 16) * 1024 * sizeof(short);

    hipLaunchKernelGGL(zero_ws_kernel, dim3(1), dim3(B_C), 0, stream, exp_sum);
    if (ws_size >= need) {
        hipLaunchKernelGGL(prep_items_kernel, dim3(NGROUPS * 128 / 256), dim3(256),
                           0, stream, item_emb, item_bf16);
        hipLaunchKernelGGL(expsum_mfma7_kernel, dim3(GX, GY), dim3(256),
                           0, stream, user_emb, item_bf16, batch_user, mask, exp_sum);
    } else {
        hipLaunchKernelGGL(expsum_fallback_kernel, dim3(64, B_C / 64), dim3(256),
                           0, stream, user_emb, item_emb, batch_user, mask, exp_sum);
    }
    hipLaunchKernelGGL(finalize_kernel, dim3(B_C), dim3(64), 0, stream,
                       user_emb, item_emb, batch_user, pos_items, top_items,
                       exp_sum, is_final, row_loss);
    hipLaunchKernelGGL(reduce_kernel, dim3(1), dim3(B_C), 0, stream, row_loss, out);
}